// Round 16
// baseline (1701.985 us; speedup 1.0000x reference)
//
#include <hip/hip_runtime.h>
#include <math.h>

#define D_MODEL 768
#define N_LAYER 8
#define D_STATE 128
#define D_CONV 4
#define HEADDIM 64
#define D_INNER 1536
#define NHEADS 24
#define D_IN_PROJ 3352   // 2*D_INNER + 2*D_STATE + NHEADS
#define CONV_DIM 1792    // D_INNER + 2*D_STATE
#define SEQLEN 1024
#define VOCAB 50288
#define EPS 1e-5f
#define T_SEG 32
#define NSEG  32         // SEQLEN / T_SEG
#define INP_PAD 3456     // D_IN_PROJ padded to 128
#define VOC_PAD 50304    // VOCAB padded to 128-tile (393 tiles of 128)

typedef __bf16 bf16x8 __attribute__((ext_vector_type(8)));
typedef float f32x4 __attribute__((ext_vector_type(4)));

__device__ inline unsigned short f2bf(float x) {
    union { float f; unsigned u; } v; v.f = x;
    unsigned r = v.u + 0x7fffu + ((v.u >> 16) & 1u);
    return (unsigned short)(r >> 16);
}
__device__ inline float bf2f(unsigned short b) {
    union { unsigned u; float f; } v; v.u = ((unsigned)b) << 16;
    return v.f;
}

// async global->LDS, 16B per lane (consecutive-lane linear dest).
__device__ __forceinline__ void gld16(unsigned short* lds, const unsigned short* g) {
    __builtin_amdgcn_global_load_lds(
        (const __attribute__((address_space(1))) unsigned int*)g,
        (__attribute__((address_space(3))) unsigned int*)lds, 16, 0, 0);
}

// ---------------- embedding gather ----------------
__global__ void k_embed(const int* __restrict__ ids, const float* __restrict__ emb,
                        float* __restrict__ x) {
    int t = blockIdx.x;
    int id = ids[t];
    const float* er = emb + (long)id * D_MODEL;
    for (int d = threadIdx.x; d < D_MODEL; d += blockDim.x)
        x[(long)t * D_MODEL + d] = er[d];
}

// ---------------- weight quant-preconvert: dst = bf16(rint(10*w)) [EXACT] ----------------
__global__ void k_wq(const float* __restrict__ src, unsigned short* __restrict__ dst,
                     int n8_per_layer, int nlayer, long dst_stride8) {
    long total = (long)n8_per_layer * nlayer;
    for (long i = (long)blockIdx.x * 256 + threadIdx.x; i < total; i += (long)gridDim.x * 256) {
        long lay = i / n8_per_layer;
        long e = i - lay * n8_per_layer;
        const float* s = src + (lay * n8_per_layer + e) * 8;
        float4 a = *(const float4*)s, b = *(const float4*)(s + 4);
        float ff[8] = {a.x, a.y, a.z, a.w, b.x, b.y, b.z, b.w};
        unsigned short h[8];
#pragma unroll
        for (int j = 0; j < 8; ++j) h[j] = f2bf(rintf(ff[j] * 10.0f));
        *(uint4*)(dst + (lay * dst_stride8 + e) * 8) =
            make_uint4(h[0] | (h[1] << 16), h[2] | (h[3] << 16),
                       h[4] | (h[5] << 16), h[6] | (h[7] << 16));
    }
}

// ---------------- LUT rmsnorm (768) -> bf16 hi/lo; also zeroes mx ----------------
__global__ void k_lutnorm(const float* __restrict__ x, const float* __restrict__ w,
                          unsigned short* __restrict__ oh, unsigned short* __restrict__ ol,
                          unsigned* __restrict__ mx) {
    __shared__ float sbuf[256];
    int t = blockIdx.x;
    if (t == 0 && threadIdx.x == 0) *mx = 0u;
    const float* xr = x + (long)t * D_MODEL;
    float ss = 0.f;
    for (int d = threadIdx.x; d < D_MODEL; d += 256) { float v = xr[d]; ss += v * v; }
    sbuf[threadIdx.x] = ss; __syncthreads();
    for (int s = 128; s > 0; s >>= 1) {
        if (threadIdx.x < s) sbuf[threadIdx.x] += sbuf[threadIdx.x + s];
        __syncthreads();
    }
    float rms = sbuf[0] / (float)D_MODEL + EPS;
    const float X0 = 1e-5f;
    const float STEP = (10.0f - 1e-5f) / 255.0f;
    int idx = (int)ceilf((rms - X0) / STEP);
    idx = min(max(idx, 0), 255);
    while (idx > 0 && (X0 + (float)(idx - 1) * STEP) >= rms) --idx;
    while (idx < 255 && (X0 + (float)idx * STEP) < rms) ++idx;
    float scale = 1.0f / sqrtf(X0 + (float)idx * STEP);
    for (int d = threadIdx.x; d < D_MODEL; d += 256) {
        float v = xr[d] * scale * w[d];
        unsigned short h = f2bf(v);
        oh[(long)t * D_MODEL + d] = h;
        ol[(long)t * D_MODEL + d] = f2bf(v - bf2f(h));
    }
}

// ======= unified MFMA GEMM: C[M,N] (+)= 0.1*(Ah+Al)[M,K] @ Bq[N,K]^T =======
// Single-buffer m97 structure (race-free), BK=64. WRxWC wave grid (threads = WR*WC*64):
// more resident waves/CU to hide the barrier drain. Optional KSPLIT via atomicAdd.
template <int BM, int BN, int WR, int WC, int PASSES, bool AMAX, bool ATOMIC, int MT, int KSPLIT>
__global__ __launch_bounds__(WR * WC * 64) void k_gemm(
    const unsigned short* __restrict__ Ah_g, const unsigned short* __restrict__ Al_g,
    const unsigned short* __restrict__ Bq_g, float* __restrict__ C,
    int N, int NT, int K, unsigned* __restrict__ mx) {

    const int i = blockIdx.x;
    const int rxcd = i & 7;
    int rest = i >> 3;
    const int xm = rest % MT; rest /= MT;          // XCD swizzle: column y's M-tiles share i%8
    const int ks = rest % KSPLIT; rest /= KSPLIT;
    const int y = rest * 8 + rxcd;
    if (y >= NT) return;
    const int bm = xm * BM, bn = y * BN;
    const int kbeg = ks * (K / KSPLIT);
    const int kend = kbeg + K / KSPLIT;

    constexpr int T   = WR * WC * 64;      // threads per block
    constexpr int MR  = BM / WR / 16;      // 16-row frags per wave
    constexpr int NR  = BN / WC / 16;      // 16-col frags per wave
    constexpr int ASL = 8 * BM;            // 16B slots per A tile (BK=64)
    constexpr int BSL = 8 * BN;

    __shared__ __align__(16) unsigned short AhL[ASL * 8];
    __shared__ __align__(16) unsigned short AlL[(PASSES == 2) ? ASL * 8 : 8];
    __shared__ __align__(16) unsigned short BqL[BSL * 8];

    const int tid = threadIdx.x;
    const int w = tid >> 6, l = tid & 63;
    const int wm = w / WC, wn = w % WC;
    const int lr = l & 15, lg = l >> 4;

    f32x4 acc[MR][NR];
#pragma unroll
    for (int m = 0; m < MR; ++m)
#pragma unroll
        for (int n = 0; n < NR; ++n) acc[m][n] = (f32x4){0.f, 0.f, 0.f, 0.f};

    for (int k0 = kbeg; k0 < kend; k0 += 64) {
#pragma unroll
        for (int j = 0; j < BSL / T; ++j) {
            int s = j * T + tid;
            int g = s / BN, r = s - g * BN;
            gld16(&BqL[s * 8], Bq_g + (size_t)(bn + r) * K + k0 + g * 8);
        }
#pragma unroll
        for (int j = 0; j < ASL / T; ++j) {
            int s = j * T + tid;
            int g = s / BM, r = s - g * BM;
            size_t goff = (size_t)(bm + r) * K + k0 + g * 8;
            gld16(&AhL[s * 8], Ah_g + goff);
            if constexpr (PASSES == 2) gld16(&AlL[s * 8], Al_g + goff);
        }
        __syncthreads();   // vmcnt(0)+lgkmcnt(0) drained by compiler before barrier

#pragma unroll
        for (int kk = 0; kk < 2; ++kk) {
            const int gq = kk * 4 + lg;    // granule index for this K-substep
            bf16x8 ah[MR], al[MR], bh[NR];
#pragma unroll
            for (int m = 0; m < MR; ++m) {
                int row = wm * (BM / WR) + m * 16 + lr;
                ah[m] = *(const bf16x8*)&AhL[(gq * BM + row) * 8];
                if constexpr (PASSES == 2) al[m] = *(const bf16x8*)&AlL[(gq * BM + row) * 8];
            }
#pragma unroll
            for (int n = 0; n < NR; ++n) {
                int row = wn * (BN / WC) + n * 16 + lr;
                bh[n] = *(const bf16x8*)&BqL[(gq * BN + row) * 8];
            }
#pragma unroll
            for (int m = 0; m < MR; ++m)
#pragma unroll
                for (int n = 0; n < NR; ++n) {
                    acc[m][n] = __builtin_amdgcn_mfma_f32_16x16x32_bf16(ah[m], bh[n], acc[m][n], 0, 0, 0);
                    if constexpr (PASSES == 2)
                        acc[m][n] = __builtin_amdgcn_mfma_f32_16x16x32_bf16(al[m], bh[n], acc[m][n], 0, 0, 0);
                }
        }
        __syncthreads();   // all reads done before next stage overwrites
    }

    float lmax = 0.f;
#pragma unroll
    for (int m = 0; m < MR; ++m) {
        int row0 = bm + wm * (BM / WR) + m * 16 + lg * 4;
#pragma unroll
        for (int n = 0; n < NR; ++n) {
            int col = bn + wn * (BN / WC) + n * 16 + lr;
            if (col < N) {
#pragma unroll
                for (int r4 = 0; r4 < 4; ++r4) {
                    float v = acc[m][n][r4] * 0.1f;
                    if (AMAX && col >= D_INNER && col < D_INNER + CONV_DIM)
                        lmax = fmaxf(lmax, fabsf(v));
                    size_t off = (size_t)(row0 + r4) * N + col;
                    if (ATOMIC) atomicAdd(&C[off], v); else C[off] = v;
                }
            }
        }
    }
    if (AMAX) {
#pragma unroll
        for (int sh = 1; sh <= 32; sh <<= 1) lmax = fmaxf(lmax, __shfl_xor(lmax, sh));
        if (l == 0) atomicMax(mx, __float_as_uint(lmax));
    }
}

// ---------------- fused quant + depthwise conv + silu ----------------
__global__ void k_convq(const float* __restrict__ zx, const float* __restrict__ qcw,
                        const float* __restrict__ cb, const float* __restrict__ cscale,
                        const unsigned* __restrict__ mx, float* __restrict__ xact) {
    int i = blockIdx.x * blockDim.x + threadIdx.x;
    if (i >= SEQLEN * CONV_DIM) return;
    float s = __uint_as_float(*mx) / (127.0f + 1e-8f);
    float inv_s = 1.0f / s;
    int t = i / CONV_DIM, c = i - t * CONV_DIM;
    float acc = cb[c];
#pragma unroll
    for (int k = 0; k < D_CONV; ++k) {
        int tt = t - (D_CONV - 1) + k;
        if (tt >= 0) {
            float q = rintf(zx[(size_t)tt * D_IN_PROJ + D_INNER + c] * inv_s);
            q = fminf(fmaxf(q, -128.0f), 127.0f);
            acc = fmaf(q, qcw[c * D_CONV + k], acc);
        }
    }
    float v = acc * (cscale[0] * s);
    xact[i] = v / (1.0f + expf(-v));
}

// ================= chunked SSM scan =================
__global__ __launch_bounds__(256) void k_scan_local(
    const float* __restrict__ xact, const float* __restrict__ zx,
    const float* __restrict__ dtbias, const float* __restrict__ A_log,
    float* __restrict__ y, float* __restrict__ hloc, float* __restrict__ dpre) {
    const int head = blockIdx.x;
    const int seg  = blockIdx.y;
    const int tid  = threadIdx.x;
    const int p  = tid >> 2;
    const int nc = tid & 3;
    const int t0 = seg * T_SEG;

    __shared__ float4 sB4[T_SEG][32];
    __shared__ float4 sC4[T_SEG][32];
    __shared__ float  sX[T_SEG][64];
    __shared__ float  sDt[T_SEG], sA[T_SEG];

#pragma unroll
    for (int it = 0; it < 4; ++it) {
        int slot = tid + it * 256;
        int t = slot >> 5, c4 = slot & 31;
        const float* rowp = xact + (size_t)(t0 + t) * CONV_DIM + D_INNER;
        float4 bv = *(const float4*)(rowp + c4 * 4);
        float4 cv = *(const float4*)(rowp + D_STATE + c4 * 4);
        int grp = c4 >> 3, r4 = c4 & 7;
        int sl = grp * 8 + ((r4 + 2 * grp) & 7);
        sB4[t][sl] = bv;
        sC4[t][sl] = cv;
    }
#pragma unroll
    for (int it = 0; it < 2; ++it) {
        int slot = tid + it * 256;
        int t = slot >> 4, c4 = slot & 15;
        *(float4*)&sX[t][c4 * 4] =
            *(const float4*)(xact + (size_t)(t0 + t) * CONV_DIM + head * HEADDIM + c4 * 4);
    }
    if (tid < T_SEG) {
        float v = zx[(size_t)(t0 + tid) * D_IN_PROJ + (D_INNER + CONV_DIM) + head] + dtbias[head];
        float dtv = fmaxf(v, 0.f) + log1pf(expf(-fabsf(v)));
        sDt[tid] = dtv;
        sA[tid] = expf(dtv * (-expf(A_log[head])));
    }
    __syncthreads();

    float h[32];
#pragma unroll
    for (int j = 0; j < 32; ++j) h[j] = 0.f;
    float d = 1.f;
    float* yrow = y + head * HEADDIM + p;

    for (int t = 0; t < T_SEG; ++t) {
        float a = sA[t], dtv = sDt[t];
        float xdt = sX[t][p] * dtv;
        d *= a;
        float acc = 0.f;
#pragma unroll
        for (int j4 = 0; j4 < 8; ++j4) {
            int sl = nc * 8 + ((j4 + 2 * nc) & 7);
            float4 Bv = sB4[t][sl];
            float4 Cv = sC4[t][sl];
            h[j4 * 4 + 0] = fmaf(a, h[j4 * 4 + 0], xdt * Bv.x); acc = fmaf(h[j4 * 4 + 0], Cv.x, acc);
            h[j4 * 4 + 1] = fmaf(a, h[j4 * 4 + 1], xdt * Bv.y); acc = fmaf(h[j4 * 4 + 1], Cv.y, acc);
            h[j4 * 4 + 2] = fmaf(a, h[j4 * 4 + 2], xdt * Bv.z); acc = fmaf(h[j4 * 4 + 2], Cv.z, acc);
            h[j4 * 4 + 3] = fmaf(a, h[j4 * 4 + 3], xdt * Bv.w); acc = fmaf(h[j4 * 4 + 3], Cv.w, acc);
        }
        acc += __shfl_xor(acc, 1);
        acc += __shfl_xor(acc, 2);
        if (nc == 0) yrow[(size_t)(t0 + t) * D_INNER] = acc;
        if (tid == 0) dpre[(head * NSEG + seg) * T_SEG + t] = d;
    }

    float* hb = hloc + ((size_t)(head * NSEG + seg) * 64 + p) * 128 + nc * 32;
#pragma unroll
    for (int j4 = 0; j4 < 8; ++j4)
        *(float4*)(hb + j4 * 4) =
            make_float4(h[j4 * 4], h[j4 * 4 + 1], h[j4 * 4 + 2], h[j4 * 4 + 3]);
}

// segment-level prefix over states, scalar floats (wide grid)
__global__ __launch_bounds__(256) void k_scan_seg(float* __restrict__ hloc,
                                                  const float* __restrict__ dpre) {
    int g = blockIdx.x * 256 + threadIdx.x;   // 196608 = 24 heads * 8192 floats
    int head = g >> 13;
    int e = g & 8191;
    float run = 0.f;
    for (int seg = 0; seg < NSEG; ++seg) {
        float d = dpre[(head * NSEG + seg) * T_SEG + (T_SEG - 1)];
        float* ptr = hloc + (size_t)(head * NSEG + seg) * 8192 + e;
        run = fmaf(d, run, *ptr);
        *ptr = run;
    }
}

__global__ __launch_bounds__(256) void k_scan_fix(
    const float* __restrict__ xact, const float* __restrict__ hloc,
    const float* __restrict__ dpre, float* __restrict__ y) {
    const int head = blockIdx.x;
    const int seg  = blockIdx.y + 1;
    const int tid  = threadIdx.x;
    const int p  = tid >> 2;
    const int nc = tid & 3;
    const int t0 = seg * T_SEG;

    __shared__ float4 sC4[T_SEG][32];
    __shared__ float  sD[T_SEG];

#pragma unroll
    for (int it = 0; it < 4; ++it) {
        int slot = tid + it * 256;
        int t = slot >> 5, c4 = slot & 31;
        float4 cv = *(const float4*)(xact + (size_t)(t0 + t) * CONV_DIM + D_INNER + D_STATE + c4 * 4);
        int grp = c4 >> 3, r4 = c4 & 7;
        sC4[t][grp * 8 + ((r4 + 2 * grp) & 7)] = cv;
    }
    if (tid < T_SEG) sD[tid] = dpre[(head * NSEG + seg) * T_SEG + tid];
    __syncthreads();

    float H[32];
    const float* hb = hloc + ((size_t)(head * NSEG + seg - 1) * 64 + p) * 128 + nc * 32;
#pragma unroll
    for (int j4 = 0; j4 < 8; ++j4) {
        float4 v = *(const float4*)(hb + j4 * 4);
        H[j4 * 4 + 0] = v.x; H[j4 * 4 + 1] = v.y; H[j4 * 4 + 2] = v.z; H[j4 * 4 + 3] = v.w;
    }
    float* yrow = y + head * HEADDIM + p;
    for (int t = 0; t < T_SEG; ++t) {
        float acc = 0.f;
#pragma unroll
        for (int j4 = 0; j4 < 8; ++j4) {
            int sl = nc * 8 + ((j4 + 2 * nc) & 7);
            float4 Cv = sC4[t][sl];
            acc = fmaf(H[j4 * 4 + 0], Cv.x, acc);
            acc = fmaf(H[j4 * 4 + 1], Cv.y, acc);
            acc = fmaf(H[j4 * 4 + 2], Cv.z, acc);
            acc = fmaf(H[j4 * 4 + 3], Cv.w, acc);
        }
        acc += __shfl_xor(acc, 1);
        acc += __shfl_xor(acc, 2);
        if (nc == 0) yrow[(size_t)(t0 + t) * D_INNER] += sD[t] * acc;
    }
}

// ---------------- gate + rmsnorm(1536) -> bf16 hi/lo ----------------
__global__ void k_gatenorm(const float* __restrict__ ybuf, const float* __restrict__ zx,
                           const float* __restrict__ xact, const float* __restrict__ dpar,
                           const float* __restrict__ mnw,
                           unsigned short* __restrict__ y3h, unsigned short* __restrict__ y3l) {
    __shared__ float sbuf[256];
    int t = blockIdx.x;
    const float* yr = ybuf + (long)t * D_INNER;
    const float* zr = zx + (long)t * D_IN_PROJ;
    const float* xa = xact + (long)t * CONV_DIM;
    float vals[6];
    float ss = 0.f;
#pragma unroll
    for (int j = 0; j < 6; ++j) {
        int e = threadIdx.x + j * 256;
        float z = zr[e];
        float v = (yr[e] + xa[e] * dpar[e >> 6]) * (z / (1.0f + expf(-z)));
        vals[j] = v; ss += v * v;
    }
    sbuf[threadIdx.x] = ss; __syncthreads();
    for (int s = 128; s > 0; s >>= 1) {
        if (threadIdx.x < s) sbuf[threadIdx.x] += sbuf[threadIdx.x + s];
        __syncthreads();
    }
    float scale = 1.0f / sqrtf(sbuf[0] / (float)D_INNER + EPS);
#pragma unroll
    for (int j = 0; j < 6; ++j) {
        int e = threadIdx.x + j * 256;
        float v = vals[j] * scale * mnw[e];
        unsigned short h = f2bf(v);
        y3h[(long)t * D_INNER + e] = h;
        y3l[(long)t * D_INNER + e] = f2bf(v - bf2f(h));
    }
}

extern "C" void kernel_launch(void* const* d_in, const int* in_sizes, int n_in,
                              void* d_out, int out_size, void* d_ws, size_t ws_size,
                              hipStream_t stream) {
    const int*   ids    = (const int*)d_in[0];
    const float* emb    = (const float*)d_in[1];
    const float* norm_w = (const float*)d_in[2];
    const float* inw    = (const float*)d_in[3];
    const float* qconv  = (const float*)d_in[4];
    const float* cscale = (const float*)d_in[5];
    const float* convb  = (const float*)d_in[6];
    const float* dtbias = (const float*)d_in[7];
    const float* alog   = (const float*)d_in[8];
    const float* dpar   = (const float*)d_in[9];
    const float* mnw    = (const float*)d_in[10];
    const float* outw   = (const float*)d_in[11];
    const float* normf  = (const float*)d_in[12];
    const float* lmw    = (const float*)d_in[13];
    float* out = (float*)d_out;

    char* base = (char*)d_ws;
    size_t off = 0;
    auto alloc = [&](size_t bytes) { char* r = base + off; off = (off + bytes + 255) & ~(size_t)255; return r; };

    float* xres = (float*)alloc((size_t)SEQLEN * D_MODEL * 4);
    float* zx   = (float*)alloc((size_t)SEQLEN * D_IN_PROJ * 4);
    float* xact = (float*)alloc((size_t)SEQLEN * CONV_DIM * 4);
    float* ybuf = (float*)alloc((size_t)SEQLEN * D_INNER * 4);
    float* hloc = (float*)alloc((size_t)NHEADS * NSEG * HEADDIM * D_STATE * 4);
    float* dpre = (float*)alloc((size_t)NHEADS * NSEG * T_SEG * 4);
    unsigned* mx = (unsigned*)alloc(64);
    unsigned short* uh  = (unsigned short*)alloc((size_t)SEQLEN * D_MODEL * 2);
    unsigned short* ul  = (unsigned short*)alloc((size_t)SEQLEN * D_MODEL * 2);
    unsigned short* y3h = (unsigned short*)alloc((size_t)SEQLEN * D_INNER * 2);
    unsigned short* y3l = (unsigned short*)alloc((size_t)SEQLEN * D_INNER * 2);
    unsigned short* inwq  = (unsigned short*)alloc((size_t)N_LAYER * INP_PAD * D_MODEL * 2);
    unsigned short* outwq = (unsigned short*)alloc((size_t)N_LAYER * D_MODEL * D_INNER * 2);
    unsigned short* lmwq  = (unsigned short*)alloc((size_t)VOC_PAD * D_MODEL * 2);

    k_embed<<<SEQLEN, 256, 0, stream>>>(ids, emb, xres);
    k_wq<<<2048, 256, 0, stream>>>(inw, inwq, D_IN_PROJ * D_MODEL / 8, N_LAYER,
                                   (long)INP_PAD * D_MODEL / 8);
    k_wq<<<2048, 256, 0, stream>>>(outw, outwq, D_MODEL * D_INNER / 8, N_LAYER,
                                   (long)D_MODEL * D_INNER / 8);
    k_wq<<<2048, 256, 0, stream>>>(lmw, lmwq, VOCAB * D_MODEL / 8, 1,
                                   (long)VOC_PAD * D_MODEL / 8);

    int nq = SEQLEN * CONV_DIM;
    for (int l = 0; l < N_LAYER; ++l) {
        k_lutnorm<<<SEQLEN, 256, 0, stream>>>(xres, norm_w + l * D_MODEL, uh, ul, mx);
        // in_proj: 64x128, 8 waves (2x4), 2-pass, AMAX. grid 8*16*4 = 512 (27 N-tiles)
        k_gemm<64, 128, 2, 4, 2, true, false, 16, 1><<<512, 512, 0, stream>>>(
            uh, ul, inwq + (size_t)l * INP_PAD * D_MODEL, zx, D_IN_PROJ, 27, D_MODEL, mx);
        k_convq<<<(nq + 255) / 256, 256, 0, stream>>>(zx, qconv + l * CONV_DIM * D_CONV,
                                                      convb + l * CONV_DIM, cscale + l, mx, xact);
        dim3 gs1(NHEADS, NSEG);
        k_scan_local<<<gs1, 256, 0, stream>>>(xact, zx, dtbias + l * NHEADS, alog + l * NHEADS,
                                              ybuf, hloc, dpre);
        k_scan_seg<<<768, 256, 0, stream>>>(hloc, dpre);
        dim3 gs3(NHEADS, NSEG - 1);
        k_scan_fix<<<gs3, 256, 0, stream>>>(xact, hloc, dpre, ybuf);
        k_gatenorm<<<SEQLEN, 256, 0, stream>>>(ybuf, zx, xact, dpar + l * NHEADS,
                                               mnw + l * D_INNER, y3h, y3l);
        // out_proj: 64x64, 4 waves (2x2), 2-pass, K-split 2, atomic residual accum.
        k_gemm<64, 64, 2, 2, 2, false, true, 16, 2><<<512, 256, 0, stream>>>(
            y3h, y3l, outwq + (size_t)l * D_MODEL * D_INNER, xres, D_MODEL, 12, D_INNER, nullptr);
    }
    k_lutnorm<<<SEQLEN, 256, 0, stream>>>(xres, normf, uh, ul, mx);
    // lm_head: 128x128, 8 waves (2x4), 1-pass. grid 8*8*50 = 3200 (393 N-tiles)
    k_gemm<128, 128, 2, 4, 1, false, false, 8, 1><<<3200, 512, 0, stream>>>(
        uh, nullptr, lmwq, out, VOCAB, 393, D_MODEL, nullptr);
}

// Round 17
// 1539.776 us; speedup vs baseline: 1.1053x; 1.1053x over previous
//
#include <hip/hip_runtime.h>
#include <math.h>

#define D_MODEL 768
#define N_LAYER 8
#define D_STATE 128
#define D_CONV 4
#define HEADDIM 64
#define D_INNER 1536
#define NHEADS 24
#define D_IN_PROJ 3352   // 2*D_INNER + 2*D_STATE + NHEADS
#define CONV_DIM 1792    // D_INNER + 2*D_STATE
#define SEQLEN 1024
#define VOCAB 50288
#define EPS 1e-5f
#define T_SEG 32
#define NSEG  32         // SEQLEN / T_SEG
#define INP_PAD 3456     // D_IN_PROJ padded to 128
#define VOC_PAD 50304    // VOCAB padded to 128-tile (393 tiles of 128)

typedef __bf16 bf16x8 __attribute__((ext_vector_type(8)));
typedef float f32x4 __attribute__((ext_vector_type(4)));

__device__ inline unsigned short f2bf(float x) {
    union { float f; unsigned u; } v; v.f = x;
    unsigned r = v.u + 0x7fffu + ((v.u >> 16) & 1u);
    return (unsigned short)(r >> 16);
}
__device__ inline float bf2f(unsigned short b) {
    union { unsigned u; float f; } v; v.u = ((unsigned)b) << 16;
    return v.f;
}

// async global->LDS, 16B per lane (consecutive-lane linear dest).
__device__ __forceinline__ void gld16(unsigned short* lds, const unsigned short* g) {
    __builtin_amdgcn_global_load_lds(
        (const __attribute__((address_space(1))) unsigned int*)g,
        (__attribute__((address_space(3))) unsigned int*)lds, 16, 0, 0);
}

// ---------------- embedding gather ----------------
__global__ void k_embed(const int* __restrict__ ids, const float* __restrict__ emb,
                        float* __restrict__ x) {
    int t = blockIdx.x;
    int id = ids[t];
    const float* er = emb + (long)id * D_MODEL;
    for (int d = threadIdx.x; d < D_MODEL; d += blockDim.x)
        x[(long)t * D_MODEL + d] = er[d];
}

// ---------------- weight quant-preconvert: dst = bf16(rint(10*w)) [EXACT] ----------------
__global__ void k_wq(const float* __restrict__ src, unsigned short* __restrict__ dst,
                     int n8_per_layer, int nlayer, long dst_stride8) {
    long total = (long)n8_per_layer * nlayer;
    for (long i = (long)blockIdx.x * 256 + threadIdx.x; i < total; i += (long)gridDim.x * 256) {
        long lay = i / n8_per_layer;
        long e = i - lay * n8_per_layer;
        const float* s = src + (lay * n8_per_layer + e) * 8;
        float4 a = *(const float4*)s, b = *(const float4*)(s + 4);
        float ff[8] = {a.x, a.y, a.z, a.w, b.x, b.y, b.z, b.w};
        unsigned short h[8];
#pragma unroll
        for (int j = 0; j < 8; ++j) h[j] = f2bf(rintf(ff[j] * 10.0f));
        *(uint4*)(dst + (lay * dst_stride8 + e) * 8) =
            make_uint4(h[0] | (h[1] << 16), h[2] | (h[3] << 16),
                       h[4] | (h[5] << 16), h[6] | (h[7] << 16));
    }
}

// ---------------- LUT rmsnorm (768) -> bf16 hi/lo; also zeroes mx ----------------
__global__ void k_lutnorm(const float* __restrict__ x, const float* __restrict__ w,
                          unsigned short* __restrict__ oh, unsigned short* __restrict__ ol,
                          unsigned* __restrict__ mx) {
    __shared__ float sbuf[256];
    int t = blockIdx.x;
    if (t == 0 && threadIdx.x == 0) *mx = 0u;
    const float* xr = x + (long)t * D_MODEL;
    float ss = 0.f;
    for (int d = threadIdx.x; d < D_MODEL; d += 256) { float v = xr[d]; ss += v * v; }
    sbuf[threadIdx.x] = ss; __syncthreads();
    for (int s = 128; s > 0; s >>= 1) {
        if (threadIdx.x < s) sbuf[threadIdx.x] += sbuf[threadIdx.x + s];
        __syncthreads();
    }
    float rms = sbuf[0] / (float)D_MODEL + EPS;
    const float X0 = 1e-5f;
    const float STEP = (10.0f - 1e-5f) / 255.0f;
    int idx = (int)ceilf((rms - X0) / STEP);
    idx = min(max(idx, 0), 255);
    while (idx > 0 && (X0 + (float)(idx - 1) * STEP) >= rms) --idx;
    while (idx < 255 && (X0 + (float)idx * STEP) < rms) ++idx;
    float scale = 1.0f / sqrtf(X0 + (float)idx * STEP);
    for (int d = threadIdx.x; d < D_MODEL; d += 256) {
        float v = xr[d] * scale * w[d];
        unsigned short h = f2bf(v);
        oh[(long)t * D_MODEL + d] = h;
        ol[(long)t * D_MODEL + d] = f2bf(v - bf2f(h));
    }
}

// ======= unified MFMA GEMM: C[M,N] (+)= 0.1*(Ah+Al)[M,K] @ Bq[N,K]^T =======
// Single-buffer m97 structure (race-free), BK=64: stage -> barrier -> 2x(ds_read+MFMA)
// -> barrier. Optional KSPLIT: each block does K/KSPLIT, accumulating via atomicAdd.
template <int BM, int BN, int PASSES, bool AMAX, bool ATOMIC, int MT, int KSPLIT>
__global__ __launch_bounds__(256) void k_gemm(
    const unsigned short* __restrict__ Ah_g, const unsigned short* __restrict__ Al_g,
    const unsigned short* __restrict__ Bq_g, float* __restrict__ C,
    int N, int NT, int K, unsigned* __restrict__ mx) {

    const int i = blockIdx.x;
    const int rxcd = i & 7;
    int rest = i >> 3;
    const int xm = rest % MT; rest /= MT;          // XCD swizzle: column y's M-tiles share i%8
    const int ks = rest % KSPLIT; rest /= KSPLIT;
    const int y = rest * 8 + rxcd;
    if (y >= NT) return;
    const int bm = xm * BM, bn = y * BN;
    const int kbeg = ks * (K / KSPLIT);
    const int kend = kbeg + K / KSPLIT;

    constexpr int MR = BM / 32;
    constexpr int NR = BN / 32;
    constexpr int ASL = 8 * BM;            // 16B slots per A tile (BK=64 -> 8 granules/row)
    constexpr int BSL = 8 * BN;

    __shared__ __align__(16) unsigned short AhL[ASL * 8];
    __shared__ __align__(16) unsigned short AlL[(PASSES == 2) ? ASL * 8 : 8];
    __shared__ __align__(16) unsigned short BqL[BSL * 8];

    const int tid = threadIdx.x;
    const int w = tid >> 6, l = tid & 63;
    const int wm = w >> 1, wn = w & 1;
    const int lr = l & 15, lg = l >> 4;

    f32x4 acc[MR][NR];
#pragma unroll
    for (int m = 0; m < MR; ++m)
#pragma unroll
        for (int n = 0; n < NR; ++n) acc[m][n] = (f32x4){0.f, 0.f, 0.f, 0.f};

    for (int k0 = kbeg; k0 < kend; k0 += 64) {
#pragma unroll
        for (int j = 0; j < BSL / 256; ++j) {
            int s = j * 256 + tid;
            int g = s / BN, r = s - g * BN;
            gld16(&BqL[s * 8], Bq_g + (size_t)(bn + r) * K + k0 + g * 8);
        }
#pragma unroll
        for (int j = 0; j < ASL / 256; ++j) {
            int s = j * 256 + tid;
            int g = s / BM, r = s - g * BM;
            size_t goff = (size_t)(bm + r) * K + k0 + g * 8;
            gld16(&AhL[s * 8], Ah_g + goff);
            if constexpr (PASSES == 2) gld16(&AlL[s * 8], Al_g + goff);
        }
        __syncthreads();   // vmcnt(0)+lgkmcnt(0) drained by compiler before barrier

#pragma unroll
        for (int kk = 0; kk < 2; ++kk) {
            const int gq = kk * 4 + lg;    // granule index for this K-substep
            bf16x8 ah[MR], al[MR], bh[NR];
#pragma unroll
            for (int m = 0; m < MR; ++m) {
                int row = wm * (BM / 2) + m * 16 + lr;
                ah[m] = *(const bf16x8*)&AhL[(gq * BM + row) * 8];
                if constexpr (PASSES == 2) al[m] = *(const bf16x8*)&AlL[(gq * BM + row) * 8];
            }
#pragma unroll
            for (int n = 0; n < NR; ++n) {
                int row = wn * (BN / 2) + n * 16 + lr;
                bh[n] = *(const bf16x8*)&BqL[(gq * BN + row) * 8];
            }
#pragma unroll
            for (int m = 0; m < MR; ++m)
#pragma unroll
                for (int n = 0; n < NR; ++n) {
                    acc[m][n] = __builtin_amdgcn_mfma_f32_16x16x32_bf16(ah[m], bh[n], acc[m][n], 0, 0, 0);
                    if constexpr (PASSES == 2)
                        acc[m][n] = __builtin_amdgcn_mfma_f32_16x16x32_bf16(al[m], bh[n], acc[m][n], 0, 0, 0);
                }
        }
        __syncthreads();   // all reads done before next stage overwrites
    }

    float lmax = 0.f;
#pragma unroll
    for (int m = 0; m < MR; ++m) {
        int row0 = bm + wm * (BM / 2) + m * 16 + lg * 4;
#pragma unroll
        for (int n = 0; n < NR; ++n) {
            int col = bn + wn * (BN / 2) + n * 16 + lr;
            if (col < N) {
#pragma unroll
                for (int r4 = 0; r4 < 4; ++r4) {
                    float v = acc[m][n][r4] * 0.1f;
                    if (AMAX && col >= D_INNER && col < D_INNER + CONV_DIM)
                        lmax = fmaxf(lmax, fabsf(v));
                    size_t off = (size_t)(row0 + r4) * N + col;
                    if (ATOMIC) atomicAdd(&C[off], v); else C[off] = v;
                }
            }
        }
    }
    if (AMAX) {
#pragma unroll
        for (int sh = 1; sh <= 32; sh <<= 1) lmax = fmaxf(lmax, __shfl_xor(lmax, sh));
        if (l == 0) atomicMax(mx, __float_as_uint(lmax));
    }
}

// ---------------- fused quant + depthwise conv + silu ----------------
__global__ void k_convq(const float* __restrict__ zx, const float* __restrict__ qcw,
                        const float* __restrict__ cb, const float* __restrict__ cscale,
                        const unsigned* __restrict__ mx, float* __restrict__ xact) {
    int i = blockIdx.x * blockDim.x + threadIdx.x;
    if (i >= SEQLEN * CONV_DIM) return;
    float s = __uint_as_float(*mx) / (127.0f + 1e-8f);
    float inv_s = 1.0f / s;
    int t = i / CONV_DIM, c = i - t * CONV_DIM;
    float acc = cb[c];
#pragma unroll
    for (int k = 0; k < D_CONV; ++k) {
        int tt = t - (D_CONV - 1) + k;
        if (tt >= 0) {
            float q = rintf(zx[(size_t)tt * D_IN_PROJ + D_INNER + c] * inv_s);
            q = fminf(fmaxf(q, -128.0f), 127.0f);
            acc = fmaf(q, qcw[c * D_CONV + k], acc);
        }
    }
    float v = acc * (cscale[0] * s);
    xact[i] = v / (1.0f + expf(-v));
}

// ================= chunked SSM scan =================
__global__ __launch_bounds__(256) void k_scan_local(
    const float* __restrict__ xact, const float* __restrict__ zx,
    const float* __restrict__ dtbias, const float* __restrict__ A_log,
    float* __restrict__ y, float* __restrict__ hloc, float* __restrict__ dpre) {
    const int head = blockIdx.x;
    const int seg  = blockIdx.y;
    const int tid  = threadIdx.x;
    const int p  = tid >> 2;
    const int nc = tid & 3;
    const int t0 = seg * T_SEG;

    __shared__ float4 sB4[T_SEG][32];
    __shared__ float4 sC4[T_SEG][32];
    __shared__ float  sX[T_SEG][64];
    __shared__ float  sDt[T_SEG], sA[T_SEG];

#pragma unroll
    for (int it = 0; it < 4; ++it) {
        int slot = tid + it * 256;
        int t = slot >> 5, c4 = slot & 31;
        const float* rowp = xact + (size_t)(t0 + t) * CONV_DIM + D_INNER;
        float4 bv = *(const float4*)(rowp + c4 * 4);
        float4 cv = *(const float4*)(rowp + D_STATE + c4 * 4);
        int grp = c4 >> 3, r4 = c4 & 7;
        int sl = grp * 8 + ((r4 + 2 * grp) & 7);
        sB4[t][sl] = bv;
        sC4[t][sl] = cv;
    }
#pragma unroll
    for (int it = 0; it < 2; ++it) {
        int slot = tid + it * 256;
        int t = slot >> 4, c4 = slot & 15;
        *(float4*)&sX[t][c4 * 4] =
            *(const float4*)(xact + (size_t)(t0 + t) * CONV_DIM + head * HEADDIM + c4 * 4);
    }
    if (tid < T_SEG) {
        float v = zx[(size_t)(t0 + tid) * D_IN_PROJ + (D_INNER + CONV_DIM) + head] + dtbias[head];
        float dtv = fmaxf(v, 0.f) + log1pf(expf(-fabsf(v)));
        sDt[tid] = dtv;
        sA[tid] = expf(dtv * (-expf(A_log[head])));
    }
    __syncthreads();

    float h[32];
#pragma unroll
    for (int j = 0; j < 32; ++j) h[j] = 0.f;
    float d = 1.f;
    float* yrow = y + head * HEADDIM + p;

    for (int t = 0; t < T_SEG; ++t) {
        float a = sA[t], dtv = sDt[t];
        float xdt = sX[t][p] * dtv;
        d *= a;
        float acc = 0.f;
#pragma unroll
        for (int j4 = 0; j4 < 8; ++j4) {
            int sl = nc * 8 + ((j4 + 2 * nc) & 7);
            float4 Bv = sB4[t][sl];
            float4 Cv = sC4[t][sl];
            h[j4 * 4 + 0] = fmaf(a, h[j4 * 4 + 0], xdt * Bv.x); acc = fmaf(h[j4 * 4 + 0], Cv.x, acc);
            h[j4 * 4 + 1] = fmaf(a, h[j4 * 4 + 1], xdt * Bv.y); acc = fmaf(h[j4 * 4 + 1], Cv.y, acc);
            h[j4 * 4 + 2] = fmaf(a, h[j4 * 4 + 2], xdt * Bv.z); acc = fmaf(h[j4 * 4 + 2], Cv.z, acc);
            h[j4 * 4 + 3] = fmaf(a, h[j4 * 4 + 3], xdt * Bv.w); acc = fmaf(h[j4 * 4 + 3], Cv.w, acc);
        }
        acc += __shfl_xor(acc, 1);
        acc += __shfl_xor(acc, 2);
        if (nc == 0) yrow[(size_t)(t0 + t) * D_INNER] = acc;
        if (tid == 0) dpre[(head * NSEG + seg) * T_SEG + t] = d;
    }

    float* hb = hloc + ((size_t)(head * NSEG + seg) * 64 + p) * 128 + nc * 32;
#pragma unroll
    for (int j4 = 0; j4 < 8; ++j4)
        *(float4*)(hb + j4 * 4) =
            make_float4(h[j4 * 4], h[j4 * 4 + 1], h[j4 * 4 + 2], h[j4 * 4 + 3]);
}

// segment-level prefix over states, scalar floats (wide grid)
__global__ __launch_bounds__(256) void k_scan_seg(float* __restrict__ hloc,
                                                  const float* __restrict__ dpre) {
    int g = blockIdx.x * 256 + threadIdx.x;   // 196608 = 24 heads * 8192 floats
    int head = g >> 13;
    int e = g & 8191;
    float run = 0.f;
    for (int seg = 0; seg < NSEG; ++seg) {
        float d = dpre[(head * NSEG + seg) * T_SEG + (T_SEG - 1)];
        float* ptr = hloc + (size_t)(head * NSEG + seg) * 8192 + e;
        run = fmaf(d, run, *ptr);
        *ptr = run;
    }
}

__global__ __launch_bounds__(256) void k_scan_fix(
    const float* __restrict__ xact, const float* __restrict__ hloc,
    const float* __restrict__ dpre, float* __restrict__ y) {
    const int head = blockIdx.x;
    const int seg  = blockIdx.y + 1;
    const int tid  = threadIdx.x;
    const int p  = tid >> 2;
    const int nc = tid & 3;
    const int t0 = seg * T_SEG;

    __shared__ float4 sC4[T_SEG][32];
    __shared__ float  sD[T_SEG];

#pragma unroll
    for (int it = 0; it < 4; ++it) {
        int slot = tid + it * 256;
        int t = slot >> 5, c4 = slot & 31;
        float4 cv = *(const float4*)(xact + (size_t)(t0 + t) * CONV_DIM + D_INNER + D_STATE + c4 * 4);
        int grp = c4 >> 3, r4 = c4 & 7;
        sC4[t][grp * 8 + ((r4 + 2 * grp) & 7)] = cv;
    }
    if (tid < T_SEG) sD[tid] = dpre[(head * NSEG + seg) * T_SEG + tid];
    __syncthreads();

    float H[32];
    const float* hb = hloc + ((size_t)(head * NSEG + seg - 1) * 64 + p) * 128 + nc * 32;
#pragma unroll
    for (int j4 = 0; j4 < 8; ++j4) {
        float4 v = *(const float4*)(hb + j4 * 4);
        H[j4 * 4 + 0] = v.x; H[j4 * 4 + 1] = v.y; H[j4 * 4 + 2] = v.z; H[j4 * 4 + 3] = v.w;
    }
    float* yrow = y + head * HEADDIM + p;
    for (int t = 0; t < T_SEG; ++t) {
        float acc = 0.f;
#pragma unroll
        for (int j4 = 0; j4 < 8; ++j4) {
            int sl = nc * 8 + ((j4 + 2 * nc) & 7);
            float4 Cv = sC4[t][sl];
            acc = fmaf(H[j4 * 4 + 0], Cv.x, acc);
            acc = fmaf(H[j4 * 4 + 1], Cv.y, acc);
            acc = fmaf(H[j4 * 4 + 2], Cv.z, acc);
            acc = fmaf(H[j4 * 4 + 3], Cv.w, acc);
        }
        acc += __shfl_xor(acc, 1);
        acc += __shfl_xor(acc, 2);
        if (nc == 0) yrow[(size_t)(t0 + t) * D_INNER] += sD[t] * acc;
    }
}

// ---------------- gate + rmsnorm(1536) -> bf16 hi/lo ----------------
__global__ void k_gatenorm(const float* __restrict__ ybuf, const float* __restrict__ zx,
                           const float* __restrict__ xact, const float* __restrict__ dpar,
                           const float* __restrict__ mnw,
                           unsigned short* __restrict__ y3h, unsigned short* __restrict__ y3l) {
    __shared__ float sbuf[256];
    int t = blockIdx.x;
    const float* yr = ybuf + (long)t * D_INNER;
    const float* zr = zx + (long)t * D_IN_PROJ;
    const float* xa = xact + (long)t * CONV_DIM;
    float vals[6];
    float ss = 0.f;
#pragma unroll
    for (int j = 0; j < 6; ++j) {
        int e = threadIdx.x + j * 256;
        float z = zr[e];
        float v = (yr[e] + xa[e] * dpar[e >> 6]) * (z / (1.0f + expf(-z)));
        vals[j] = v; ss += v * v;
    }
    sbuf[threadIdx.x] = ss; __syncthreads();
    for (int s = 128; s > 0; s >>= 1) {
        if (threadIdx.x < s) sbuf[threadIdx.x] += sbuf[threadIdx.x + s];
        __syncthreads();
    }
    float scale = 1.0f / sqrtf(sbuf[0] / (float)D_INNER + EPS);
#pragma unroll
    for (int j = 0; j < 6; ++j) {
        int e = threadIdx.x + j * 256;
        float v = vals[j] * scale * mnw[e];
        unsigned short h = f2bf(v);
        y3h[(long)t * D_INNER + e] = h;
        y3l[(long)t * D_INNER + e] = f2bf(v - bf2f(h));
    }
}

extern "C" void kernel_launch(void* const* d_in, const int* in_sizes, int n_in,
                              void* d_out, int out_size, void* d_ws, size_t ws_size,
                              hipStream_t stream) {
    const int*   ids    = (const int*)d_in[0];
    const float* emb    = (const float*)d_in[1];
    const float* norm_w = (const float*)d_in[2];
    const float* inw    = (const float*)d_in[3];
    const float* qconv  = (const float*)d_in[4];
    const float* cscale = (const float*)d_in[5];
    const float* convb  = (const float*)d_in[6];
    const float* dtbias = (const float*)d_in[7];
    const float* alog   = (const float*)d_in[8];
    const float* dpar   = (const float*)d_in[9];
    const float* mnw    = (const float*)d_in[10];
    const float* outw   = (const float*)d_in[11];
    const float* normf  = (const float*)d_in[12];
    const float* lmw    = (const float*)d_in[13];
    float* out = (float*)d_out;

    char* base = (char*)d_ws;
    size_t off = 0;
    auto alloc = [&](size_t bytes) { char* r = base + off; off = (off + bytes + 255) & ~(size_t)255; return r; };

    float* xres = (float*)alloc((size_t)SEQLEN * D_MODEL * 4);
    float* zx   = (float*)alloc((size_t)SEQLEN * D_IN_PROJ * 4);
    float* xact = (float*)alloc((size_t)SEQLEN * CONV_DIM * 4);
    float* ybuf = (float*)alloc((size_t)SEQLEN * D_INNER * 4);
    float* hloc = (float*)alloc((size_t)NHEADS * NSEG * HEADDIM * D_STATE * 4);
    float* dpre = (float*)alloc((size_t)NHEADS * NSEG * T_SEG * 4);
    unsigned* mx = (unsigned*)alloc(64);
    unsigned short* uh  = (unsigned short*)alloc((size_t)SEQLEN * D_MODEL * 2);
    unsigned short* ul  = (unsigned short*)alloc((size_t)SEQLEN * D_MODEL * 2);
    unsigned short* y3h = (unsigned short*)alloc((size_t)SEQLEN * D_INNER * 2);
    unsigned short* y3l = (unsigned short*)alloc((size_t)SEQLEN * D_INNER * 2);
    unsigned short* inwq  = (unsigned short*)alloc((size_t)N_LAYER * INP_PAD * D_MODEL * 2);
    unsigned short* outwq = (unsigned short*)alloc((size_t)N_LAYER * D_MODEL * D_INNER * 2);
    unsigned short* lmwq  = (unsigned short*)alloc((size_t)VOC_PAD * D_MODEL * 2);

    k_embed<<<SEQLEN, 256, 0, stream>>>(ids, emb, xres);
    k_wq<<<2048, 256, 0, stream>>>(inw, inwq, D_IN_PROJ * D_MODEL / 8, N_LAYER,
                                   (long)INP_PAD * D_MODEL / 8);
    k_wq<<<2048, 256, 0, stream>>>(outw, outwq, D_MODEL * D_INNER / 8, N_LAYER,
                                   (long)D_MODEL * D_INNER / 8);
    k_wq<<<2048, 256, 0, stream>>>(lmw, lmwq, VOCAB * D_MODEL / 8, 1,
                                   (long)VOC_PAD * D_MODEL / 8);

    int nq = SEQLEN * CONV_DIM;
    for (int l = 0; l < N_LAYER; ++l) {
        k_lutnorm<<<SEQLEN, 256, 0, stream>>>(xres, norm_w + l * D_MODEL, uh, ul, mx);
        // in_proj: 64x128, 2-pass, AMAX. grid 8*16*1*4 = 512 (27 N-tiles)
        k_gemm<64, 128, 2, true, false, 16, 1><<<512, 256, 0, stream>>>(
            uh, ul, inwq + (size_t)l * INP_PAD * D_MODEL, zx, D_IN_PROJ, 27, D_MODEL, mx);
        k_convq<<<(nq + 255) / 256, 256, 0, stream>>>(zx, qconv + l * CONV_DIM * D_CONV,
                                                      convb + l * CONV_DIM, cscale + l, mx, xact);
        dim3 gs1(NHEADS, NSEG);
        k_scan_local<<<gs1, 256, 0, stream>>>(xact, zx, dtbias + l * NHEADS, alog + l * NHEADS,
                                              ybuf, hloc, dpre);
        k_scan_seg<<<768, 256, 0, stream>>>(hloc, dpre);
        dim3 gs3(NHEADS, NSEG - 1);
        k_scan_fix<<<gs3, 256, 0, stream>>>(xact, hloc, dpre, ybuf);
        k_gatenorm<<<SEQLEN, 256, 0, stream>>>(ybuf, zx, xact, dpar + l * NHEADS,
                                               mnw + l * D_INNER, y3h, y3l);
        // out_proj: 64x64, 2-pass, K-split 2, atomic residual accum.
        // grid = 8 * 16 * 2 * 2 = 512 (12 N-tiles, 2 K-halves)
        k_gemm<64, 64, 2, false, true, 16, 2><<<512, 256, 0, stream>>>(
            y3h, y3l, outwq + (size_t)l * D_MODEL * D_INNER, xres, D_MODEL, 12, D_INNER, nullptr);
    }
    k_lutnorm<<<SEQLEN, 256, 0, stream>>>(xres, normf, uh, ul, mx);
    // lm_head: 128x128, 1-pass. 8 M-tiles x 393 N-tiles -> grid 8*8*50 = 3200
    k_gemm<128, 128, 1, false, false, 8, 1><<<3200, 256, 0, stream>>>(
        uh, nullptr, lmwq, out, VOCAB, 393, D_MODEL, nullptr);
}